// Round 3
// baseline (242.848 us; speedup 1.0000x reference)
//
#include <hip/hip_runtime.h>
#include <stdint.h>

typedef short v8s __attribute__((ext_vector_type(8)));
typedef short v4s __attribute__((ext_vector_type(4)));
typedef float v4f __attribute__((ext_vector_type(4)));

#define AS1 __attribute__((address_space(1)))
#define AS3 __attribute__((address_space(3)))

__device__ __forceinline__ void glds16(const void* g, void* l) {
  __builtin_amdgcn_global_load_lds((const AS1 void*)g, (AS3 void*)l, 16, 0, 0);
}

__device__ __forceinline__ short f2bf(float f) {
  uint32_t u = __float_as_uint(f);
  u += 0x7fffu + ((u >> 16) & 1u);   // RNE; inputs are finite
  return (short)(u >> 16);
}

#define MFMA16(A, B, C) __builtin_amdgcn_mfma_f32_16x16x32_bf16(A, B, C, 0, 0, 0)

// ---------------- fused prep: input casts + all weight transposes ----------------
// flat grid 13312: blocks [0,768) per-head W transpose, [768,1024) Wo transpose,
// [1024,13312) fp32->bf16 casts. Transpose blocks dispatch first (latency-bound),
// cast blocks (HBM-bound) stream behind and overlap them.
__global__ __launch_bounds__(256) void prep_kernel(
    const float* __restrict__ xQ, const float* __restrict__ xK, const float* __restrict__ xV,
    const float* __restrict__ wq, const float* __restrict__ wk, const float* __restrict__ wv,
    const float* __restrict__ wo,
    short* __restrict__ oxQ, short* __restrict__ oxK, short* __restrict__ oxV,
    short* __restrict__ oq, short* __restrict__ ok, short* __restrict__ ov,
    short* __restrict__ oo) {
  const int bid = blockIdx.x;
  const int t = threadIdx.x;
  if (bid >= 1024) {
    const int c = bid - 1024;
    const int z = c >> 12;
    const int i = (c & 4095) * 256 + t;
    const float* in = (z == 0) ? xQ : (z == 1) ? xK : xV;
    short* out      = (z == 0) ? oxQ : (z == 1) ? oxK : oxV;
    float4 v = ((const float4*)in)[i];
    short4 o = { f2bf(v.x), f2bf(v.y), f2bf(v.z), f2bf(v.w) };
    ((short4*)out)[i] = o;
    return;
  }
  __shared__ float tile[64][65];
  const float* in;
  short* out;
  int C, R, rb, cb;
  if (bid < 768) {
    const int which = bid >> 8, rem = bid & 255;
    const int slice = rem >> 4, rbi = rem & 15;
    in  = ((which == 0) ? wq : (which == 1) ? wk : wv) + (size_t)slice * 65536;
    out = ((which == 0) ? oq : (which == 1) ? ok : ov) + (size_t)slice * 65536;
    C = 64; R = 1024; rb = rbi * 64; cb = 0;
  } else {
    const int r = bid - 768;
    in = wo; out = oo;
    C = 1024; R = 1024; rb = (r >> 4) * 64; cb = (r & 15) * 64;
  }
  const int col = t & 63, r0 = t >> 6;
#pragma unroll
  for (int i = 0; i < 16; ++i) {
    int row = r0 + i * 4;
    tile[row][col] = in[(size_t)(rb + row) * C + cb + col];
  }
  __syncthreads();
#pragma unroll
  for (int i = 0; i < 16; ++i) {
    int orow = r0 + i * 4;
    out[(size_t)(cb + orow) * R + rb + col] = f2bf(tile[col][orow]);
  }
}

// ---------------- MRx128 GEMM core — A: async 3-buffer LDS; B: global->reg -------
// B (weight panel, L2-resident) skips LDS entirely: per wave 4x b128 scattered
// loads per K-step into double-buffered reg slots, prefetched 2 steps ahead.
// Halves LDS port traffic (the measured bottleneck: reads 32->16KB, DMA 16->8KB
// per block-step). vmcnt ledger (per sub-iter issues A-DMA then 4 B-loads; order
// within a barrier region may swap, ledger holds either way):
//   prologue A0,A1,B0,B1 -> first wait vmcnt(4); steady wait vmcnt(6) [MR=128]
//   or vmcnt(5) [MR=64] = exactly {A(kb+1),B(kb+1)} outstanding.
// NOTE: SQ_LDS_BANK_CONFLICT floor of 8 per glds16 (DMA 1KB write = 8 LDS cyc).
template <int MR>
__device__ __forceinline__ void gemm_core(const short* __restrict__ Ag,
                                          const short* __restrict__ Bg,
                                          short* As,
                                          v4f (&acc)[MR / 32][4]) {
  constexpr int MT = MR / 32;
  constexpr int ASZ = MR * 32;     // shorts per A buffer
  const int tid  = threadIdx.x;
  const int lane = tid & 63;
  const int w    = tid >> 6;
  const int quad = lane >> 4;
  const int c15  = lane & 15;
  const int wr   = (w >> 1) * (MR / 2);
  const int wc   = (w & 1) * 64;

  const int r0 = tid >> 2;
  const int p0 = (tid & 3) ^ ((r0 & 3) ^ ((r0 >> 2) & 3));
  const short* a0 = Ag + (size_t)r0 * 1024 + p0 * 8;
  const short* a1 = a0 + 64 * 1024;
  short* lA = As + tid * 8;

  auto issueA = [&](int t, int buf) {
    const int o = t * 32;
    glds16(a0 + o, lA + buf * ASZ);
    if constexpr (MR == 128) glds16(a1 + o, lA + buf * ASZ + 2048);
  };

  // B frag rows are n-dim (stride 1024); one wave b128 load = 16 full 64B lines.
  const short* Bw = Bg + (size_t)(wc + c15) * 1024 + quad * 8;
  auto loadB = [&](v8s (&bb)[4], int t) {
    const int o = t * 32;
#pragma unroll
    for (int nt = 0; nt < 4; ++nt)
      bb[nt] = *(const v8s*)(Bw + nt * 16384 + o);
  };

  auto waitbar = [] {
    if constexpr (MR == 128)
      asm volatile("s_waitcnt vmcnt(6)\n\ts_barrier" ::: "memory");
    else
      asm volatile("s_waitcnt vmcnt(5)\n\ts_barrier" ::: "memory");
  };

  const int xs = (c15 & 3) ^ ((c15 >> 2) & 3);
  const int rdoff = ((quad ^ xs)) * 8;

  auto compute = [&](int kb, v8s (&bb)[4]) {
    const short* Ab = As + (kb % 3) * ASZ;
    v8s a[MT];
#pragma unroll
    for (int mt = 0; mt < MT; ++mt)
      a[mt] = *(const v8s*)(Ab + (wr + mt * 16 + c15) * 32 + rdoff);
#pragma unroll
    for (int mt = 0; mt < MT; ++mt)
#pragma unroll
      for (int nt = 0; nt < 4; ++nt)
        acc[mt][nt] = MFMA16(a[mt], bb[nt], acc[mt][nt]);
  };

  v8s bA[4], bB[4];
  issueA(0, 0); issueA(1, 1);
  loadB(bA, 0); loadB(bB, 1);

  // kb = 0
  asm volatile("s_waitcnt vmcnt(4)\n\ts_barrier" ::: "memory");
  issueA(2, 2);
  compute(0, bA);
  loadB(bA, 2);

  for (int p = 0; p < 15; ++p) {
    const int kb = 2 * p + 1;                 // odd sub-iter: consumes bB
    waitbar();
    issueA(kb + 2, (kb + 2) % 3);             // kb+2 <= 31 here
    compute(kb, bB);
    loadB(bB, kb + 2);
    const int k2 = kb + 1;                    // even sub-iter: consumes bA
    waitbar();
    {
      const int tn = (k2 + 2 < 32) ? k2 + 2 : 31;   // p=14: clamp (junk, unread)
      issueA(tn, (k2 + 2) % 3);
      compute(k2, bA);
      loadB(bA, tn);
    }
  }
  // kb = 31 (no further issues; kb=30's clamped issues keep vmcnt ledger exact)
  waitbar();
  compute(31, bB);
}

// ---------------- QKV projection (128x128 tiles, XCD-patch swizzle) ----------------
__global__ __launch_bounds__(256, 3) void proj_gemm(
    const short* __restrict__ xQ, const short* __restrict__ xK, const short* __restrict__ xV,
    const short* __restrict__ WqT, const short* __restrict__ WkT, const short* __restrict__ WvT,
    const float* __restrict__ bq, const float* __restrict__ bk, const float* __restrict__ bv,
    short* __restrict__ Qb, short* __restrict__ Kb, short* __restrict__ Vtb) {
  __shared__ short As[12288];                  // 3 bufs x 128x32 bf16
  const int lin = blockIdx.x;
  const int z = lin >> 8;
  const int r = lin & 255;
  const int nb = ((r >> 3) & 7) * 128;
  const int mb = (((r & 7) << 2) + (r >> 6)) * 128;
  const short* A    = (z == 0) ? xQ  : (z == 1) ? xK  : xV;
  const short* Bt   = (z == 0) ? WqT : (z == 1) ? WkT : WvT;
  const float* bias = (z == 0) ? bq  : (z == 1) ? bk  : bv;
  short* outp       = (z == 0) ? Qb  : (z == 1) ? Kb  : Vtb;
  v4f acc[4][4] = {};
  gemm_core<128>(A + (size_t)mb * 1024, Bt + (size_t)nb * 1024, As, acc);

  const int lane = threadIdx.x & 63, w = threadIdx.x >> 6;
  const int quad = lane >> 4, c15 = lane & 15;
  const int wr = (w >> 1) * 64, wc = (w & 1) * 64;
  const bool vmode = (z == 2);
#pragma unroll
  for (int nt = 0; nt < 4; ++nt) {
    const int gn = nb + wc + nt * 16 + c15;
    const float bb = bias[gn];
    const int h = gn >> 6, e = gn & 63;
#pragma unroll
    for (int mt = 0; mt < 4; ++mt) {
      if (!vmode) {
#pragma unroll
        for (int rr = 0; rr < 4; ++rr) {
          const int gm = mb + wr + mt * 16 + quad * 4 + rr;
          const int bi = gm >> 10, s = gm & 1023;
          const size_t base = (size_t)(bi * 16 + h) * 65536;
          outp[base + (size_t)s * 64 + e] = f2bf(acc[mt][nt][rr] + bb);
        }
      } else {
        const int gm0 = mb + wr + mt * 16 + quad * 4;
        const int bi = gm0 >> 10, s0 = gm0 & 1023;
        const size_t base = (size_t)(bi * 16 + h) * 65536;
        short4 st = { f2bf(acc[mt][nt][0] + bb), f2bf(acc[mt][nt][1] + bb),
                      f2bf(acc[mt][nt][2] + bb), f2bf(acc[mt][nt][3] + bb) };
        *(short4*)&outp[base + (size_t)e * 1024 + s0] = st;
      }
    }
  }
}

// ---------------- output projection (64x128 tiles, XCD-patch swizzle) ----------------
__global__ __launch_bounds__(256, 3) void out_gemm(
    const short* __restrict__ AV, const short* __restrict__ WoT,
    const float* __restrict__ bo, float* __restrict__ outp) {
  __shared__ short As[6144];                   // 3 bufs x 64x32 bf16
  const int lin = blockIdx.x;
  const int nb = ((lin >> 3) & 7) * 128;
  const int mb = (((lin & 7) << 3) + (lin >> 6)) * 64;
  v4f acc[2][4] = {};
  gemm_core<64>(AV + (size_t)mb * 1024, WoT + (size_t)nb * 1024, As, acc);
  const int lane = threadIdx.x & 63, w = threadIdx.x >> 6;
  const int quad = lane >> 4, c15 = lane & 15;
  const int wr = (w >> 1) * 32, wc = (w & 1) * 64;
#pragma unroll
  for (int nt = 0; nt < 4; ++nt) {
    const int gn = nb + wc + nt * 16 + c15;
    const float bb = bo[gn];
#pragma unroll
    for (int mt = 0; mt < 2; ++mt)
#pragma unroll
      for (int r = 0; r < 4; ++r) {
        const int gm = mb + wr + mt * 16 + quad * 4 + r;
        outp[(size_t)gm * 1024 + gn] = acc[mt][nt][r] + bb;
      }
  }
}

// ---------------- flash attention: grid 512 (2 blocks/CU), 4 waves x 32 q-rows ----
// q-rows/block 128: 2 query-frags per wave. 2 blocks/CU cross-cover the
// __syncthreads vmcnt(0) drain (m114 overlap). K/V tiles L2-resident per XCD.
__global__ __launch_bounds__(256, 2) void attn_kernel(
    const short* __restrict__ Qb, const short* __restrict__ Kb,
    const short* __restrict__ Vtb, const int* __restrict__ lens,
    short* __restrict__ AVb) {
  __shared__ short Ks[2][4096];
  __shared__ short Vs[2][4096];
  const int tid = threadIdx.x, lane = tid & 63, w = tid >> 6;   // w 0..3
  const int quad = lane >> 4, c15 = lane & 15;
  const int flat = blockIdx.x;
  const int bh = (flat & 7) + 8 * ((flat >> 3) & 7);   // all 8 q-blocks of bh on one XCD
  const int qg = flat >> 6;                            // 0..7, 128 q-rows each
  const int b = bh >> 4, h = bh & 15;
  const short* Qp = Qb  + (size_t)bh * 65536;
  const short* Kp = Kb  + (size_t)bh * 65536;
  const short* Vp = Vtb + (size_t)bh * 65536;
  const int len = lens[b];
  const int row0 = qg * 128 + w * 32;    // this wave's 32 q-rows (2 frags of 16)

  // Q as B-operand frags: B[n=query=c15][k=dh=kf*32+quad*8+j], per query-frag qf
  v8s bq_[2][2];
#pragma unroll
  for (int qf = 0; qf < 2; ++qf)
#pragma unroll
    for (int kf = 0; kf < 2; ++kf)
      bq_[qf][kf] = *(const v8s*)(Qp + (size_t)(row0 + qf * 16 + c15) * 64 + kf * 32 + quad * 8);

  // masked query rows: scale=0 -> P=1 uniformly -> softmax = 1/S (matches reference)
  float scale[2];
  scale[0] = (row0 + c15 < len) ? 0.125f : 0.0f;
  scale[1] = (row0 + 16 + c15 < len) ? 0.125f : 0.0f;
  float sm[2] = {0.f, 0.f};
  v4f o[2][4] = {};          // O^T per qf: row=dh=t*16+quad*4+r, col=query=c15

  // staging: K/V tiles 8KB each; 256 threads x 2 chunks of 16B.
  // row=chunk>>3, LDS part=chunk&7, global part = part ^ (row&7)
  const int srow = tid >> 3, spart = tid & 7;
  const int gpart = spart ^ (srow & 7);
  const int kgo0 = srow * 64 + gpart * 8, kgo1 = (srow + 32) * 64 + gpart * 8;
  const int vgo0 = srow * 1024 + gpart * 8, vgo1 = (srow + 32) * 1024 + gpart * 8;
  const int l0 = tid * 8, l1 = 2048 + tid * 8;

  const int c7 = c15 & 7;
  const int krow = c15 * 128;
  const int koff0 = krow + ((quad) ^ c7) * 16;
  const int koff1 = krow + ((4 + quad) ^ c7) * 16;
  const int q2 = quad >> 1, h8 = (quad & 1) * 8;
  int voff[4];
#pragma unroll
  for (int nt = 0; nt < 4; ++nt)
    voff[nt] = krow + ((2 * nt + q2) ^ c7) * 16 + h8;

  glds16(Kp + kgo0, (char*)Ks[0] + l0 * 2);
  glds16(Kp + kgo1, (char*)Ks[0] + l1 * 2);
  glds16(Vp + vgo0, (char*)Vs[0] + l0 * 2);
  glds16(Vp + vgo1, (char*)Vs[0] + l1 * 2);

  for (int kb = 0; kb < 16; ++kb) {
    const int cur = kb & 1, nxt = cur ^ 1;
    __syncthreads();

    if (kb < 15) {
      const short* kt = Kp + (size_t)(kb + 1) * 4096;
      const short* vt = Vp + (kb + 1) * 64;
      glds16(kt + kgo0, (char*)Ks[nxt] + l0 * 2);
      glds16(kt + kgo1, (char*)Ks[nxt] + l1 * 2);
      glds16(vt + vgo0, (char*)Vs[nxt] + l0 * 2);
      glds16(vt + vgo1, (char*)Vs[nxt] + l1 * 2);
    }

    // K A-frags from LDS: A[m=key=c15][k=dh]
    v8s ak[4][2];
#pragma unroll
    for (int nt = 0; nt < 4; ++nt) {
      ak[nt][0] = *(const v8s*)((const char*)Ks[cur] + nt * 2048 + koff0);
      ak[nt][1] = *(const v8s*)((const char*)Ks[cur] + nt * 2048 + koff1);
    }

    // S^T = K Q^T (per query-frag)
    v4f sc[2][4];
#pragma unroll
    for (int qf = 0; qf < 2; ++qf)
#pragma unroll
      for (int nt = 0; nt < 4; ++nt) {
        v4f z = {};
#pragma unroll
        for (int kf = 0; kf < 2; ++kf)
          z = __builtin_amdgcn_mfma_f32_16x16x32_bf16(ak[nt][kf], bq_[qf][kf], z, 0, 0, 0);
        sc[qf][nt] = z;
      }

    // softmax numerator in-register
    v4s pb[2][4];
#pragma unroll
    for (int qf = 0; qf < 2; ++qf)
#pragma unroll
      for (int nt = 0; nt < 4; ++nt) {
        v4s pv;
#pragma unroll
        for (int r = 0; r < 4; ++r) {
          float p = __expf(sc[qf][nt][r] * scale[qf]);
          sm[qf] += p;
          pv[r] = f2bf(p);
        }
        pb[qf][nt] = pv;
      }

    // V^T A-frags after exp (ak dead -> av live: VGPR headroom)
    v4s av[4][4];
#pragma unroll
    for (int t = 0; t < 4; ++t)
#pragma unroll
      for (int nt = 0; nt < 4; ++nt)
        av[t][nt] = *(const v4s*)((const char*)Vs[cur] + t * 2048 + voff[nt]);

    // O^T += V^T P^T
#pragma unroll
    for (int t = 0; t < 4; ++t)
#pragma unroll
      for (int nt = 0; nt < 4; ++nt) {
        o[0][t] = __builtin_amdgcn_mfma_f32_16x16x16bf16_1k(av[t][nt], pb[0][nt], o[0][t], 0, 0, 0);
        o[1][t] = __builtin_amdgcn_mfma_f32_16x16x16bf16_1k(av[t][nt], pb[1][nt], o[1][t], 0, 0, 0);
      }
  }

#pragma unroll
  for (int qf = 0; qf < 2; ++qf) {
    float s = sm[qf];
    s += __shfl_xor(s, 16);
    s += __shfl_xor(s, 32);
    const float inv = 1.0f / s;
    const size_t rowbase = (size_t)(b * 1024 + row0 + qf * 16 + c15) * 1024 + h * 64;
#pragma unroll
    for (int t = 0; t < 4; ++t) {
      short4 st = { f2bf(o[qf][t][0] * inv), f2bf(o[qf][t][1] * inv),
                    f2bf(o[qf][t][2] * inv), f2bf(o[qf][t][3] * inv) };
      *(short4*)&AVb[rowbase + t * 16 + quad * 4] = st;
    }
  }
}

// ---------------- launch ----------------
extern "C" void kernel_launch(void* const* d_in, const int* in_sizes, int n_in,
                              void* d_out, int out_size, void* d_ws, size_t ws_size,
                              hipStream_t stream) {
  const float* xQ = (const float*)d_in[0];
  const float* xK = (const float*)d_in[1];
  const float* xV = (const float*)d_in[2];
  const int* lens = (const int*)d_in[3];
  const float* Wq = (const float*)d_in[4];
  const float* bq = (const float*)d_in[5];
  const float* Wk = (const float*)d_in[6];
  const float* bk = (const float*)d_in[7];
  const float* Wv = (const float*)d_in[8];
  const float* bv = (const float*)d_in[9];
  const float* Wo = (const float*)d_in[10];
  const float* bo = (const float*)d_in[11];
  float* out = (float*)d_out;

  char* ws = (char*)d_ws;
  short* xQb = (short*)(ws + 0);                 // 8 MB  [4096][1024] bf16
  short* xKb = (short*)(ws + 8388608);
  short* xVb = (short*)(ws + 16777216);
  short* WqT = (short*)(ws + 25165824);          // 2 MB  [n=h*64+e][d]
  short* WkT = (short*)(ws + 27262976);
  short* WvT = (short*)(ws + 29360128);
  short* WoT = (short*)(ws + 31457280);          // 2 MB  Wo^T [n][k]
  short* Qb  = (short*)(ws + 33554432);          // 8 MB  [b,h,s,e]
  short* Kb  = (short*)(ws + 41943040);          // 8 MB  [b,h,s,e]
  short* Vtb = (short*)(ws + 50331648);          // 8 MB  [b,h,e,s]
  short* AVb = (short*)(ws + 58720256);          // 8 MB  [b,s,h*64+e]

  prep_kernel<<<dim3(13312), 256, 0, stream>>>(xQ, xK, xV, Wq, Wk, Wv, Wo,
                                               xQb, xKb, xVb, WqT, WkT, WvT, WoT);
  proj_gemm<<<dim3(768), 256, 0, stream>>>(xQb, xKb, xVb, WqT, WkT, WvT,
                                           bq, bk, bv, Qb, Kb, Vtb);
  attn_kernel<<<dim3(512), 256, 0, stream>>>(Qb, Kb, Vtb, lens, AVb);
  out_gemm<<<dim3(512), 256, 0, stream>>>(AVb, WoT, bo, out);
}

// Round 4
// 202.604 us; speedup vs baseline: 1.1986x; 1.1986x over previous
//
#include <hip/hip_runtime.h>
#include <stdint.h>

typedef short v8s __attribute__((ext_vector_type(8)));
typedef short v4s __attribute__((ext_vector_type(4)));
typedef float v4f __attribute__((ext_vector_type(4)));

#define AS1 __attribute__((address_space(1)))
#define AS3 __attribute__((address_space(3)))

__device__ __forceinline__ void glds16(const void* g, void* l) {
  __builtin_amdgcn_global_load_lds((const AS1 void*)g, (AS3 void*)l, 16, 0, 0);
}

__device__ __forceinline__ short f2bf(float f) {
  uint32_t u = __float_as_uint(f);
  u += 0x7fffu + ((u >> 16) & 1u);   // RNE; inputs are finite
  return (short)(u >> 16);
}

// ---------------- fused prep: input casts + all weight transposes ----------------
// flat grid 13312: blocks [0,768) per-head W transpose, [768,1024) Wo transpose,
// [1024,13312) fp32->bf16 casts. Transpose blocks dispatch first (latency-bound),
// cast blocks (HBM-bound) stream behind and overlap them.
__global__ __launch_bounds__(256) void prep_kernel(
    const float* __restrict__ xQ, const float* __restrict__ xK, const float* __restrict__ xV,
    const float* __restrict__ wq, const float* __restrict__ wk, const float* __restrict__ wv,
    const float* __restrict__ wo,
    short* __restrict__ oxQ, short* __restrict__ oxK, short* __restrict__ oxV,
    short* __restrict__ oq, short* __restrict__ ok, short* __restrict__ ov,
    short* __restrict__ oo) {
  const int bid = blockIdx.x;
  const int t = threadIdx.x;
  if (bid >= 1024) {
    const int c = bid - 1024;
    const int z = c >> 12;
    const int i = (c & 4095) * 256 + t;
    const float* in = (z == 0) ? xQ : (z == 1) ? xK : xV;
    short* out      = (z == 0) ? oxQ : (z == 1) ? oxK : oxV;
    float4 v = ((const float4*)in)[i];
    short4 o = { f2bf(v.x), f2bf(v.y), f2bf(v.z), f2bf(v.w) };
    ((short4*)out)[i] = o;
    return;
  }
  __shared__ float tile[64][65];
  const float* in;
  short* out;
  int C, R, rb, cb;
  if (bid < 768) {
    const int which = bid >> 8, rem = bid & 255;
    const int slice = rem >> 4, rbi = rem & 15;
    in  = ((which == 0) ? wq : (which == 1) ? wk : wv) + (size_t)slice * 65536;
    out = ((which == 0) ? oq : (which == 1) ? ok : ov) + (size_t)slice * 65536;
    C = 64; R = 1024; rb = rbi * 64; cb = 0;
  } else {
    const int r = bid - 768;
    in = wo; out = oo;
    C = 1024; R = 1024; rb = (r >> 4) * 64; cb = (r & 15) * 64;
  }
  const int col = t & 63, r0 = t >> 6;
#pragma unroll
  for (int i = 0; i < 16; ++i) {
    int row = r0 + i * 4;
    tile[row][col] = in[(size_t)(rb + row) * C + cb + col];
  }
  __syncthreads();
#pragma unroll
  for (int i = 0; i < 16; ++i) {
    int orow = r0 + i * 4;
    out[(size_t)(cb + orow) * R + rb + col] = f2bf(tile[col][orow]);
  }
}

// ---------------- MRx128 GEMM core — async 3-buffer pipeline + XOR bank swizzle ----
// NOTE: SQ_LDS_BANK_CONFLICT has a fixed floor of 8 per glds16 (DMA 1KB write =
// 8 LDS cycles) — 3.1M for proj is that artifact, not real read conflicts.
// R3 lesson: B must stay in LDS via coalesced glds16 — per-wave scattered global
// b128 B-loads (16 lines/instr) choke the TA and regress 1.5x.
template <int MR>
__device__ __forceinline__ void gemm_core(const short* __restrict__ Ag,
                                          const short* __restrict__ Bg,
                                          short* As, short* Bs,
                                          v4f (&acc)[MR / 32][4]) {
  constexpr int MT = MR / 32;
  constexpr int ASZ = MR * 32;     // shorts per A buffer
  constexpr int BSZ = 128 * 32;    // shorts per B buffer
  const int tid  = threadIdx.x;
  const int lane = tid & 63;
  const int w    = tid >> 6;
  const int quad = lane >> 4;
  const int c15  = lane & 15;
  const int wr   = (w >> 1) * (MR / 2);
  const int wc   = (w & 1) * 64;

  const int r0 = tid >> 2;
  const int p0 = (tid & 3) ^ ((r0 & 3) ^ ((r0 >> 2) & 3));
  const short* a0 = Ag + (size_t)r0 * 1024 + p0 * 8;
  const short* a1 = a0 + 64 * 1024;
  const short* b0 = Bg + (size_t)r0 * 1024 + p0 * 8;
  const short* b1 = b0 + 64 * 1024;
  short* lA = As + tid * 8;
  short* lB = Bs + tid * 8;

  auto issue = [&](int t, int buf) {
    const int o = t * 32;
    glds16(a0 + o, lA + buf * ASZ);
    if constexpr (MR == 128) glds16(a1 + o, lA + buf * ASZ + 2048);
    glds16(b0 + o, lB + buf * BSZ);
    glds16(b1 + o, lB + buf * BSZ + 2048);
  };

  issue(0, 0);
  issue(1, 1);

  const int xs = (c15 & 3) ^ ((c15 >> 2) & 3);
  const int rdoff = ((quad ^ xs)) * 8;

  for (int kb = 0; kb < 32; ++kb) {
    if constexpr (MR == 128)
      asm volatile("s_waitcnt vmcnt(4)\n\ts_barrier" ::: "memory");
    else
      asm volatile("s_waitcnt vmcnt(3)\n\ts_barrier" ::: "memory");

    const int t2 = kb + 2;
    issue(t2 < 32 ? t2 : 31, t2 % 3);

    const short* Ab = As + (kb % 3) * ASZ;
    const short* Bb = Bs + (kb % 3) * BSZ;

    v8s a[MT], b[4];
#pragma unroll
    for (int mt = 0; mt < MT; ++mt)
      a[mt] = *(const v8s*)(Ab + (wr + mt * 16 + c15) * 32 + rdoff);
#pragma unroll
    for (int nt = 0; nt < 4; ++nt)
      b[nt] = *(const v8s*)(Bb + (wc + nt * 16 + c15) * 32 + rdoff);
#pragma unroll
    for (int mt = 0; mt < MT; ++mt)
#pragma unroll
      for (int nt = 0; nt < 4; ++nt)
        acc[mt][nt] = __builtin_amdgcn_mfma_f32_16x16x32_bf16(a[mt], b[nt], acc[mt][nt], 0, 0, 0);
  }
}

// ---------------- QKV projection (128x128 tiles, XCD-patch swizzle) ----------------
__global__ __launch_bounds__(256, 3) void proj_gemm(
    const short* __restrict__ xQ, const short* __restrict__ xK, const short* __restrict__ xV,
    const short* __restrict__ WqT, const short* __restrict__ WkT, const short* __restrict__ WvT,
    const float* __restrict__ bq, const float* __restrict__ bk, const float* __restrict__ bv,
    short* __restrict__ Qb, short* __restrict__ Kb, short* __restrict__ Vtb) {
  __shared__ short As[12288];
  __shared__ short Bs[12288];
  const int lin = blockIdx.x;
  const int z = lin >> 8;
  const int r = lin & 255;
  const int nb = ((r >> 3) & 7) * 128;
  const int mb = (((r & 7) << 2) + (r >> 6)) * 128;
  const short* A    = (z == 0) ? xQ  : (z == 1) ? xK  : xV;
  const short* Bt   = (z == 0) ? WqT : (z == 1) ? WkT : WvT;
  const float* bias = (z == 0) ? bq  : (z == 1) ? bk  : bv;
  short* outp       = (z == 0) ? Qb  : (z == 1) ? Kb  : Vtb;
  v4f acc[4][4] = {};
  gemm_core<128>(A + (size_t)mb * 1024, Bt + (size_t)nb * 1024, As, Bs, acc);

  const int lane = threadIdx.x & 63, w = threadIdx.x >> 6;
  const int quad = lane >> 4, c15 = lane & 15;
  const int wr = (w >> 1) * 64, wc = (w & 1) * 64;
  const bool vmode = (z == 2);
#pragma unroll
  for (int nt = 0; nt < 4; ++nt) {
    const int gn = nb + wc + nt * 16 + c15;
    const float bb = bias[gn];
    const int h = gn >> 6, e = gn & 63;
#pragma unroll
    for (int mt = 0; mt < 4; ++mt) {
      if (!vmode) {
#pragma unroll
        for (int rr = 0; rr < 4; ++rr) {
          const int gm = mb + wr + mt * 16 + quad * 4 + rr;
          const int bi = gm >> 10, s = gm & 1023;
          const size_t base = (size_t)(bi * 16 + h) * 65536;
          outp[base + (size_t)s * 64 + e] = f2bf(acc[mt][nt][rr] + bb);
        }
      } else {
        const int gm0 = mb + wr + mt * 16 + quad * 4;
        const int bi = gm0 >> 10, s0 = gm0 & 1023;
        const size_t base = (size_t)(bi * 16 + h) * 65536;
        short4 st = { f2bf(acc[mt][nt][0] + bb), f2bf(acc[mt][nt][1] + bb),
                      f2bf(acc[mt][nt][2] + bb), f2bf(acc[mt][nt][3] + bb) };
        *(short4*)&outp[base + (size_t)e * 1024 + s0] = st;
      }
    }
  }
}

// ---------------- output projection (64x128 tiles, XCD-patch swizzle) ----------------
__global__ __launch_bounds__(256, 3) void out_gemm(
    const short* __restrict__ AV, const short* __restrict__ WoT,
    const float* __restrict__ bo, float* __restrict__ outp) {
  __shared__ short As[6144];
  __shared__ short Bs[12288];
  const int lin = blockIdx.x;
  const int nb = ((lin >> 3) & 7) * 128;
  const int mb = (((lin & 7) << 3) + (lin >> 6)) * 64;
  v4f acc[2][4] = {};
  gemm_core<64>(AV + (size_t)mb * 1024, WoT + (size_t)nb * 1024, As, Bs, acc);
  const int lane = threadIdx.x & 63, w = threadIdx.x >> 6;
  const int quad = lane >> 4, c15 = lane & 15;
  const int wr = (w >> 1) * 32, wc = (w & 1) * 64;
#pragma unroll
  for (int nt = 0; nt < 4; ++nt) {
    const int gn = nb + wc + nt * 16 + c15;
    const float bb = bo[gn];
#pragma unroll
    for (int mt = 0; mt < 2; ++mt)
#pragma unroll
      for (int r = 0; r < 4; ++r) {
        const int gm = mb + wr + mt * 16 + quad * 4 + r;
        outp[(size_t)gm * 1024 + gn] = acc[mt][nt][r] + bb;
      }
  }
}

// ---------------- flash attention: grid 512 (2 blocks/CU), 4 waves x 32 q-rows ----
// 3-buffer K/V pipeline with counted vmcnt (T3/T4 ledger, gemm_core-style):
// per iter {vmcnt(4); s_barrier; issue tile kb+2; compute kb}. Tile kb+2 lands in
// buf (kb-1)%3, whose readers finished before this barrier (write-after-read safe);
// vmcnt(4) retires tile kb (and, on iter 0, the older Q-loads) while tile kb+1
// stays in flight — the old __syncthreads drained the just-issued prefetch 16x.
__global__ __launch_bounds__(256, 2) void attn_kernel(
    const short* __restrict__ Qb, const short* __restrict__ Kb,
    const short* __restrict__ Vtb, const int* __restrict__ lens,
    short* __restrict__ AVb) {
  __shared__ short Ks[3][4096];
  __shared__ short Vs[3][4096];
  const int tid = threadIdx.x, lane = tid & 63, w = tid >> 6;   // w 0..3
  const int quad = lane >> 4, c15 = lane & 15;
  const int flat = blockIdx.x;
  const int bh = (flat & 7) + 8 * ((flat >> 3) & 7);   // all 8 q-blocks of bh on one XCD
  const int qg = flat >> 6;                            // 0..7, 128 q-rows each
  const int b = bh >> 4, h = bh & 15;
  const short* Qp = Qb  + (size_t)bh * 65536;
  const short* Kp = Kb  + (size_t)bh * 65536;
  const short* Vp = Vtb + (size_t)bh * 65536;
  const int len = lens[b];
  const int row0 = qg * 128 + w * 32;    // this wave's 32 q-rows (2 frags of 16)

  // Q as B-operand frags: B[n=query=c15][k=dh=kf*32+quad*8+j], per query-frag qf
  v8s bq_[2][2];
#pragma unroll
  for (int qf = 0; qf < 2; ++qf)
#pragma unroll
    for (int kf = 0; kf < 2; ++kf)
      bq_[qf][kf] = *(const v8s*)(Qp + (size_t)(row0 + qf * 16 + c15) * 64 + kf * 32 + quad * 8);

  // masked query rows: scale=0 -> P=1 uniformly -> softmax = 1/S (matches reference)
  float scale[2];
  scale[0] = (row0 + c15 < len) ? 0.125f : 0.0f;
  scale[1] = (row0 + 16 + c15 < len) ? 0.125f : 0.0f;
  float sm[2] = {0.f, 0.f};
  v4f o[2][4] = {};          // O^T per qf: row=dh=t*16+quad*4+r, col=query=c15

  // staging: K/V tiles 8KB each; 256 threads x 2 chunks of 16B.
  // row=chunk>>3, LDS part=chunk&7, global part = part ^ (row&7)
  const int srow = tid >> 3, spart = tid & 7;
  const int gpart = spart ^ (srow & 7);
  const int kgo0 = srow * 64 + gpart * 8, kgo1 = (srow + 32) * 64 + gpart * 8;
  const int vgo0 = srow * 1024 + gpart * 8, vgo1 = (srow + 32) * 1024 + gpart * 8;
  const int l0 = tid * 8, l1 = 2048 + tid * 8;

  const int c7 = c15 & 7;
  const int krow = c15 * 128;
  const int koff0 = krow + ((quad) ^ c7) * 16;
  const int koff1 = krow + ((4 + quad) ^ c7) * 16;
  const int q2 = quad >> 1, h8 = (quad & 1) * 8;
  int voff[4];
#pragma unroll
  for (int nt = 0; nt < 4; ++nt)
    voff[nt] = krow + ((2 * nt + q2) ^ c7) * 16 + h8;

  auto issue = [&](int t) {                  // 4 glds16 for tile t into buf t%3
    const short* kt = Kp + (size_t)t * 4096;
    const short* vt = Vp + t * 64;
    char* kd = (char*)Ks[t % 3];
    char* vd = (char*)Vs[t % 3];
    glds16(kt + kgo0, kd + l0 * 2);
    glds16(kt + kgo1, kd + l1 * 2);
    glds16(vt + vgo0, vd + l0 * 2);
    glds16(vt + vgo1, vd + l1 * 2);
  };

  auto compute = [&](int kb) {
    const char* kc = (const char*)Ks[kb % 3];
    const char* vc = (const char*)Vs[kb % 3];
    // K A-frags from LDS: A[m=key=c15][k=dh]
    v8s ak[4][2];
#pragma unroll
    for (int nt = 0; nt < 4; ++nt) {
      ak[nt][0] = *(const v8s*)(kc + nt * 2048 + koff0);
      ak[nt][1] = *(const v8s*)(kc + nt * 2048 + koff1);
    }
    // S^T = K Q^T (per query-frag)
    v4f sc[2][4];
#pragma unroll
    for (int qf = 0; qf < 2; ++qf)
#pragma unroll
      for (int nt = 0; nt < 4; ++nt) {
        v4f z = {};
#pragma unroll
        for (int kf = 0; kf < 2; ++kf)
          z = __builtin_amdgcn_mfma_f32_16x16x32_bf16(ak[nt][kf], bq_[qf][kf], z, 0, 0, 0);
        sc[qf][nt] = z;
      }
    // softmax numerator in-register
    v4s pb[2][4];
#pragma unroll
    for (int qf = 0; qf < 2; ++qf)
#pragma unroll
      for (int nt = 0; nt < 4; ++nt) {
        v4s pv;
#pragma unroll
        for (int r = 0; r < 4; ++r) {
          float p = __expf(sc[qf][nt][r] * scale[qf]);
          sm[qf] += p;
          pv[r] = f2bf(p);
        }
        pb[qf][nt] = pv;
      }
    // V^T A-frags after exp (ak dead -> av live: VGPR headroom)
    v4s av[4][4];
#pragma unroll
    for (int t = 0; t < 4; ++t)
#pragma unroll
      for (int nt = 0; nt < 4; ++nt)
        av[t][nt] = *(const v4s*)(vc + t * 2048 + voff[nt]);
    // O^T += V^T P^T
#pragma unroll
    for (int t = 0; t < 4; ++t)
#pragma unroll
      for (int nt = 0; nt < 4; ++nt) {
        o[0][t] = __builtin_amdgcn_mfma_f32_16x16x16bf16_1k(av[t][nt], pb[0][nt], o[0][t], 0, 0, 0);
        o[1][t] = __builtin_amdgcn_mfma_f32_16x16x16bf16_1k(av[t][nt], pb[1][nt], o[1][t], 0, 0, 0);
      }
  };

  issue(0);
  issue(1);

  for (int kb = 0; kb < 15; ++kb) {
    // vmcnt(4): tile kb (and iter-0's Q-loads, which are older) retired;
    // tile kb+1's 4 loads stay in flight across the barrier.
    asm volatile("s_waitcnt vmcnt(4)\n\ts_barrier" ::: "memory");
    if (kb <= 13) issue(kb + 2);
    compute(kb);
  }
  asm volatile("s_waitcnt vmcnt(0)\n\ts_barrier" ::: "memory");
  compute(15);

#pragma unroll
  for (int qf = 0; qf < 2; ++qf) {
    float s = sm[qf];
    s += __shfl_xor(s, 16);
    s += __shfl_xor(s, 32);
    const float inv = 1.0f / s;
    const size_t rowbase = (size_t)(b * 1024 + row0 + qf * 16 + c15) * 1024 + h * 64;
#pragma unroll
    for (int t = 0; t < 4; ++t) {
      short4 st = { f2bf(o[qf][t][0] * inv), f2bf(o[qf][t][1] * inv),
                    f2bf(o[qf][t][2] * inv), f2bf(o[qf][t][3] * inv) };
      *(short4*)&AVb[rowbase + t * 16 + quad * 4] = st;
    }
  }
}

// ---------------- launch ----------------
extern "C" void kernel_launch(void* const* d_in, const int* in_sizes, int n_in,
                              void* d_out, int out_size, void* d_ws, size_t ws_size,
                              hipStream_t stream) {
  const float* xQ = (const float*)d_in[0];
  const float* xK = (const float*)d_in[1];
  const float* xV = (const float*)d_in[2];
  const int* lens = (const int*)d_in[3];
  const float* Wq = (const float*)d_in[4];
  const float* bq = (const float*)d_in[5];
  const float* Wk = (const float*)d_in[6];
  const float* bk = (const float*)d_in[7];
  const float* Wv = (const float*)d_in[8];
  const float* bv = (const float*)d_in[9];
  const float* Wo = (const float*)d_in[10];
  const float* bo = (const float*)d_in[11];
  float* out = (float*)d_out;

  char* ws = (char*)d_ws;
  short* xQb = (short*)(ws + 0);                 // 8 MB  [4096][1024] bf16
  short* xKb = (short*)(ws + 8388608);
  short* xVb = (short*)(ws + 16777216);
  short* WqT = (short*)(ws + 25165824);          // 2 MB  [n=h*64+e][d]
  short* WkT = (short*)(ws + 27262976);
  short* WvT = (short*)(ws + 29360128);
  short* WoT = (short*)(ws + 31457280);          // 2 MB  Wo^T [n][k]
  short* Qb  = (short*)(ws + 33554432);          // 8 MB  [b,h,s,e]
  short* Kb  = (short*)(ws + 41943040);          // 8 MB  [b,h,s,e]
  short* Vtb = (short*)(ws + 50331648);          // 8 MB  [b,h,e,s]
  short* AVb = (short*)(ws + 58720256);          // 8 MB  [b,s,h*64+e]

  prep_kernel<<<dim3(13312), 256, 0, stream>>>(xQ, xK, xV, Wq, Wk, Wv, Wo,
                                               xQb, xKb, xVb, WqT, WkT, WvT, WoT);
  proj_gemm<<<dim3(768), 256, 0, stream>>>(xQb, xKb, xVb, WqT, WkT, WvT,
                                           bq, bk, bv, Qb, Kb, Vtb);
  attn_kernel<<<dim3(512), 256, 0, stream>>>(Qb, Kb, Vtb, lens, AVb);
  out_gemm<<<dim3(512), 256, 0, stream>>>(AVb, WoT, bo, out);
}